// Round 2
// baseline (996.916 us; speedup 1.0000x reference)
//
#include <hip/hip_runtime.h>

#define NN 100000
#define NE 1600000
#define F 128
#define SCAN_CHUNK 2048
#define NB_SCAN ((NN + SCAN_CHUNK - 1) / SCAN_CHUNK)   // 49

typedef __bf16 bf16x8 __attribute__((ext_vector_type(8)));
typedef float  f32x4  __attribute__((ext_vector_type(4)));

__device__ inline unsigned short f2bf(float f) {
    unsigned int u = __float_as_uint(f);
    unsigned int r = (u + 0x7FFFu + ((u >> 16) & 1u)) >> 16;
    return (unsigned short)r;
}
__device__ inline float bf2f(unsigned short h) {
    return __uint_as_float(((unsigned int)h) << 16);
}

// ---------------- CSR build ----------------
__global__ void k_hist(const int* __restrict__ dst, int* __restrict__ deg) {
    int stride = gridDim.x * blockDim.x;
    for (int e = blockIdx.x * blockDim.x + threadIdx.x; e < NE; e += stride)
        atomicAdd(&deg[dst[e]], 1);
}

__global__ void k_scan_part(const int* __restrict__ deg, int* __restrict__ partial) {
    __shared__ int sdata[256];
    int base = blockIdx.x * SCAN_CHUNK;
    int sum = 0;
    for (int j = threadIdx.x; j < SCAN_CHUNK; j += 256) {
        int idx = base + j;
        sum += (idx < NN) ? deg[idx] : 0;
    }
    sdata[threadIdx.x] = sum;
    __syncthreads();
    for (int s = 128; s > 0; s >>= 1) {
        if (threadIdx.x < s) sdata[threadIdx.x] += sdata[threadIdx.x + s];
        __syncthreads();
    }
    if (threadIdx.x == 0) partial[blockIdx.x] = sdata[0];
}

__global__ void k_scan_mid(int* __restrict__ partial) {
    if (threadIdx.x == 0) {
        int acc = 0;
        for (int i = 0; i < NB_SCAN; ++i) { int v = partial[i]; partial[i] = acc; acc += v; }
    }
}

__global__ void k_scan_final(const int* __restrict__ deg, const int* __restrict__ partial,
                             int* __restrict__ row_ptr, int* __restrict__ cursor) {
    __shared__ int svals[SCAN_CHUNK];
    __shared__ int ssum[256];
    int base = blockIdx.x * SCAN_CHUNK;
    for (int j = threadIdx.x; j < SCAN_CHUNK; j += 256) {
        int idx = base + j;
        svals[j] = (idx < NN) ? deg[idx] : 0;
    }
    __syncthreads();
    int t0 = threadIdx.x * 8;
    int loc[8];
    int s = 0;
#pragma unroll
    for (int k = 0; k < 8; ++k) { loc[k] = s; s += svals[t0 + k]; }
    ssum[threadIdx.x] = s;
    __syncthreads();
    for (int off = 1; off < 256; off <<= 1) {
        int v = (threadIdx.x >= off) ? ssum[threadIdx.x - off] : 0;
        __syncthreads();
        ssum[threadIdx.x] += v;
        __syncthreads();
    }
    int texcl = (threadIdx.x == 0) ? 0 : ssum[threadIdx.x - 1];
    int offbase = partial[blockIdx.x] + texcl;
#pragma unroll
    for (int k = 0; k < 8; ++k) {
        int idx = base + t0 + k;
        if (idx < NN) {
            int v = offbase + loc[k];
            row_ptr[idx] = v;
            cursor[idx]  = v;
        }
    }
    if (blockIdx.x == 0 && threadIdx.x == 0) row_ptr[NN] = NE;
}

__global__ void k_fill(const int* __restrict__ src, const int* __restrict__ dst,
                       int* __restrict__ cursor, int* __restrict__ csr) {
    int stride = gridDim.x * blockDim.x;
    for (int e = blockIdx.x * blockDim.x + threadIdx.x; e < NE; e += stride) {
        int d = dst[e];
        int p = atomicAdd(&cursor[d], 1);
        csr[p] = src[e];
    }
}

// ---------------- aggregation: u[i] = hin[i] + sum_{j in N(i)} hin[j] ----------------
__global__ void k_agg(const float* __restrict__ hin, const int* __restrict__ row_ptr,
                      const int* __restrict__ csr, float* __restrict__ u) {
    int half = threadIdx.x >> 5;        // 0..7
    int l32  = threadIdx.x & 31;
    int node = blockIdx.x * 8 + half;
    if (node >= NN) return;
    const float4* rowin = (const float4*)(hin + (size_t)node * F);
    float4 acc = rowin[l32];
    int s = row_ptr[node], e = row_ptr[node + 1];
    for (int p = s; p < e; ++p) {
        int j = csr[p];
        float4 v = ((const float4*)(hin + (size_t)j * F))[l32];
        acc.x += v.x; acc.y += v.y; acc.z += v.z; acc.w += v.w;
    }
    ((float4*)(u + (size_t)node * F))[l32] = acc;
}

// ---------------- weight split: W[k][n] fp32 -> Wt_hi/Wt_lo [n][k] bf16 ----------------
struct WPack {
    const float* w[5];
    unsigned short* hi[5];
    unsigned short* lo[5];
};

__global__ void k_wsplit_all(WPack p) {
    int which = blockIdx.x >> 6;                     // 64 blocks per matrix
    int idx = (blockIdx.x & 63) * 256 + threadIdx.x; // over n*128+k
    int n = idx >> 7, k = idx & 127;
    float v = p.w[which][k * 128 + n];
    unsigned short h = f2bf(v);
    float r = v - bf2f(h);
    p.hi[which][idx] = h;
    p.lo[which][idx] = f2bf(r);
}

// ---------------- MFMA split-bf16 GEMM: C[M,128] = A[M,128] @ W[128,128] + bias ----------------
// Block: 256 thr (4 waves), tile 128x128. A staged in LDS as hi/lo bf16, 16B-granule XOR swizzle.
// W given transposed+split: Wt[n][k]. 3 MFMAs per product term pair (hi*hi + hi*lo + lo*hi).
template <int RELU>
__global__ __launch_bounds__(256, 2) void k_gemm_mfma(const float* __restrict__ A,
                                                      const unsigned short* __restrict__ Whi,
                                                      const unsigned short* __restrict__ Wlo,
                                                      const float* __restrict__ bias,
                                                      float* __restrict__ C) {
    __shared__ __align__(16) unsigned short sAhi[128 * 128];
    __shared__ __align__(16) unsigned short sAlo[128 * 128];

    const int tid = threadIdx.x;
    const int row0 = blockIdx.x * 128;

    // ---- stage A (fp32 global -> hi/lo bf16 LDS, swizzled) ----
    {
        int r = tid >> 1;
        int cbase = (tid & 1) * 64;
        int grow = row0 + r;
        const float4* src4 = (const float4*)(A + (size_t)grow * F + cbase);
#pragma unroll
        for (int i = 0; i < 16; ++i) {
            float4 v = make_float4(0.f, 0.f, 0.f, 0.f);
            if (grow < NN) v = src4[i];
            ushort4 h, l;
            h.x = f2bf(v.x); l.x = f2bf(v.x - bf2f(h.x));
            h.y = f2bf(v.y); l.y = f2bf(v.y - bf2f(h.y));
            h.z = f2bf(v.z); l.z = f2bf(v.z - bf2f(h.z));
            h.w = f2bf(v.w); l.w = f2bf(v.w - bf2f(h.w));
            int c = cbase + i * 4;
            int u = c >> 3;
            int addr = r * 128 + ((u ^ (r & 15)) << 3) + (c & 7);
            *(ushort4*)&sAhi[addr] = h;
            *(ushort4*)&sAlo[addr] = l;
        }
    }
    __syncthreads();

    // ---- compute ----
    const int wave = tid >> 6;       // 0..3 -> rows [wave*32, wave*32+32)
    const int lane = tid & 63;
    const int m16  = lane & 15;
    const int quad = lane >> 4;      // 0..3

    f32x4 acc[2][8] = {};

#pragma unroll
    for (int ks = 0; ks < 4; ++ks) {
        bf16x8 a_hi[2], a_lo[2];
#pragma unroll
        for (int rt = 0; rt < 2; ++rt) {
            int rowLocal = wave * 32 + rt * 16 + m16;
            int u = ks * 4 + quad;
            int aoff = rowLocal * 128 + ((u ^ m16) << 3);
            a_hi[rt] = *(const bf16x8*)&sAhi[aoff];
            a_lo[rt] = *(const bf16x8*)&sAlo[aoff];
        }
#pragma unroll
        for (int ct = 0; ct < 8; ++ct) {
            int widx = (ct * 16 + m16) * 128 + ks * 32 + quad * 8;
            bf16x8 bh = *(const bf16x8*)&Whi[widx];
            bf16x8 bl = *(const bf16x8*)&Wlo[widx];
#pragma unroll
            for (int rt = 0; rt < 2; ++rt) {
                acc[rt][ct] = __builtin_amdgcn_mfma_f32_16x16x32_bf16(a_hi[rt], bh, acc[rt][ct], 0, 0, 0);
                acc[rt][ct] = __builtin_amdgcn_mfma_f32_16x16x32_bf16(a_hi[rt], bl, acc[rt][ct], 0, 0, 0);
                acc[rt][ct] = __builtin_amdgcn_mfma_f32_16x16x32_bf16(a_lo[rt], bh, acc[rt][ct], 0, 0, 0);
            }
        }
    }

    // ---- epilogue: bias (+relu), store ----
    const int rbase = row0 + wave * 32;
#pragma unroll
    for (int rt = 0; rt < 2; ++rt) {
#pragma unroll
        for (int ct = 0; ct < 8; ++ct) {
            int col = ct * 16 + m16;
            float bv = bias[col];
#pragma unroll
            for (int i = 0; i < 4; ++i) {
                int row = rbase + rt * 16 + quad * 4 + i;
                if (row < NN) {
                    float v = acc[rt][ct][i] + bv;
                    if (RELU) v = fmaxf(v, 0.f);
                    C[(size_t)row * F + col] = v;
                }
            }
        }
    }
}

// ---------------- final layer: out[i] = dot(t[i], w) + b ----------------
__global__ void k_final(const float* __restrict__ t, const float* __restrict__ w,
                        const float* __restrict__ b, float* __restrict__ out) {
    int wv = threadIdx.x >> 6;
    int lane = threadIdx.x & 63;
    int node = blockIdx.x * 4 + wv;
    if (node >= NN) return;
    float2 a  = ((const float2*)(t + (size_t)node * F))[lane];
    float2 ww = ((const float2*)w)[lane];
    float s = a.x * ww.x + a.y * ww.y;
#pragma unroll
    for (int off = 32; off > 0; off >>= 1) s += __shfl_down(s, off, 64);
    if (lane == 0) out[node] = s + b[0];
}

// ---------------- launch ----------------
static inline size_t align256(size_t x) { return (x + 255) & ~(size_t)255; }

extern "C" void kernel_launch(void* const* d_in, const int* in_sizes, int n_in,
                              void* d_out, int out_size, void* d_ws, size_t ws_size,
                              hipStream_t stream) {
    const float* x   = (const float*)d_in[0];
    const int*   ei  = (const int*)d_in[1];
    const float* w11 = (const float*)d_in[2];
    const float* b11 = (const float*)d_in[3];
    const float* w12 = (const float*)d_in[4];
    const float* b12 = (const float*)d_in[5];
    const float* w21 = (const float*)d_in[6];
    const float* b21 = (const float*)d_in[7];
    const float* w22 = (const float*)d_in[8];
    const float* b22 = (const float*)d_in[9];
    const float* w31 = (const float*)d_in[10];
    const float* b31 = (const float*)d_in[11];
    const float* w32 = (const float*)d_in[12];
    const float* b32 = (const float*)d_in[13];
    float* out = (float*)d_out;

    const int* src = ei;
    const int* dst = ei + NE;

    char* ws = (char*)d_ws;
    size_t off = 0;
    float* buf0 = (float*)(ws + off); off += align256((size_t)NN * F * 4);
    float* buf1 = (float*)(ws + off); off += align256((size_t)NN * F * 4);
    int* deg     = (int*)(ws + off); off += align256((size_t)NN * 4);
    int* row_ptr = (int*)(ws + off); off += align256((size_t)(NN + 1) * 4);
    int* cursor  = (int*)(ws + off); off += align256((size_t)NN * 4);
    int* partial = (int*)(ws + off); off += align256((size_t)NB_SCAN * 4);
    int* csr     = (int*)(ws + off); off += align256((size_t)NE * 4);
    unsigned short* whi[5];
    unsigned short* wlo[5];
    for (int i = 0; i < 5; ++i) {
        whi[i] = (unsigned short*)(ws + off); off += align256((size_t)128 * 128 * 2);
        wlo[i] = (unsigned short*)(ws + off); off += align256((size_t)128 * 128 * 2);
    }
    (void)ws_size;

    // ---- weight split (all 5 128x128 weights) ----
    WPack wp;
    wp.w[0] = w11; wp.w[1] = w12; wp.w[2] = w21; wp.w[3] = w22; wp.w[4] = w31;
    for (int i = 0; i < 5; ++i) { wp.hi[i] = whi[i]; wp.lo[i] = wlo[i]; }
    k_wsplit_all<<<320, 256, 0, stream>>>(wp);

    // ---- CSR build ----
    hipMemsetAsync(deg, 0, (size_t)NN * 4, stream);
    k_hist<<<2048, 256, 0, stream>>>(dst, deg);
    k_scan_part<<<NB_SCAN, 256, 0, stream>>>(deg, partial);
    k_scan_mid<<<1, 64, 0, stream>>>(partial);
    k_scan_final<<<NB_SCAN, 256, 0, stream>>>(deg, partial, row_ptr, cursor);
    k_fill<<<2048, 256, 0, stream>>>(src, dst, cursor, csr);

    const int aggBlocks  = (NN + 7) / 8;
    const int gemmBlocks = (NN + 127) / 128;

    // ---- layer 1 ----
    k_agg<<<aggBlocks, 256, 0, stream>>>(x, row_ptr, csr, buf0);
    k_gemm_mfma<1><<<gemmBlocks, 256, 0, stream>>>(buf0, whi[0], wlo[0], b11, buf1);
    k_gemm_mfma<0><<<gemmBlocks, 256, 0, stream>>>(buf1, whi[1], wlo[1], b12, buf0);
    // ---- layer 2 ----
    k_agg<<<aggBlocks, 256, 0, stream>>>(buf0, row_ptr, csr, buf1);
    k_gemm_mfma<1><<<gemmBlocks, 256, 0, stream>>>(buf1, whi[2], wlo[2], b21, buf0);
    k_gemm_mfma<0><<<gemmBlocks, 256, 0, stream>>>(buf0, whi[3], wlo[3], b22, buf1);
    // ---- layer 3 ----
    k_agg<<<aggBlocks, 256, 0, stream>>>(buf1, row_ptr, csr, buf0);
    k_gemm_mfma<1><<<gemmBlocks, 256, 0, stream>>>(buf0, whi[4], wlo[4], b31, buf1);
    k_final<<<(NN + 3) / 4, 256, 0, stream>>>(buf1, w32, b32, out);
}

// Round 4
// 844.268 us; speedup vs baseline: 1.1808x; 1.1808x over previous
//
#include <hip/hip_runtime.h>

#define NN 100000
#define NE 1600000
#define F 128
#define SCAN_CHUNK 2048
#define NB_SCAN ((NN + SCAN_CHUNK - 1) / SCAN_CHUNK)   // 49

typedef __bf16 bf16x8 __attribute__((ext_vector_type(8)));
typedef float  f32x4  __attribute__((ext_vector_type(4)));
typedef unsigned short ushort8v __attribute__((ext_vector_type(8)));
typedef unsigned short ushort4v __attribute__((ext_vector_type(4)));

__device__ inline float bf2f(unsigned short h) { return __uint_as_float(((unsigned int)h) << 16); }
// truncation split: v == bf2f(hi) + bf2f(lo) (hi = truncate, lo = bf16(v - hi))
// returns hi in bits [15:0], lo in bits [31:16]
__device__ inline unsigned int split2u(float v) {
    unsigned int u = __float_as_uint(v);
    unsigned int hi = u >> 16;
    float hf = __uint_as_float(u & 0xFFFF0000u);
    unsigned int lo = __float_as_uint(v - hf) >> 16;
    return hi | (lo << 16);
}

// ---------------- CSR build ----------------
__global__ void k_hist(const int* __restrict__ dst, int* __restrict__ deg) {
    int stride = gridDim.x * blockDim.x;
    for (int e = blockIdx.x * blockDim.x + threadIdx.x; e < NE; e += stride)
        atomicAdd(&deg[dst[e]], 1);
}

__global__ void k_scan_part(const int* __restrict__ deg, int* __restrict__ partial) {
    __shared__ int sdata[256];
    int base = blockIdx.x * SCAN_CHUNK;
    int sum = 0;
    for (int j = threadIdx.x; j < SCAN_CHUNK; j += 256) {
        int idx = base + j;
        sum += (idx < NN) ? deg[idx] : 0;
    }
    sdata[threadIdx.x] = sum;
    __syncthreads();
    for (int s = 128; s > 0; s >>= 1) {
        if (threadIdx.x < s) sdata[threadIdx.x] += sdata[threadIdx.x + s];
        __syncthreads();
    }
    if (threadIdx.x == 0) partial[blockIdx.x] = sdata[0];
}

__global__ void k_scan_mid(int* __restrict__ partial) {
    if (threadIdx.x == 0) {
        int acc = 0;
        for (int i = 0; i < NB_SCAN; ++i) { int v = partial[i]; partial[i] = acc; acc += v; }
    }
}

__global__ void k_scan_final(const int* __restrict__ deg, const int* __restrict__ partial,
                             int* __restrict__ row_ptr, int* __restrict__ cursor) {
    __shared__ int svals[SCAN_CHUNK];
    __shared__ int ssum[256];
    int base = blockIdx.x * SCAN_CHUNK;
    for (int j = threadIdx.x; j < SCAN_CHUNK; j += 256) {
        int idx = base + j;
        svals[j] = (idx < NN) ? deg[idx] : 0;
    }
    __syncthreads();
    int t0 = threadIdx.x * 8;
    int loc[8];
    int s = 0;
#pragma unroll
    for (int k = 0; k < 8; ++k) { loc[k] = s; s += svals[t0 + k]; }
    ssum[threadIdx.x] = s;
    __syncthreads();
    for (int off = 1; off < 256; off <<= 1) {
        int v = (threadIdx.x >= off) ? ssum[threadIdx.x - off] : 0;
        __syncthreads();
        ssum[threadIdx.x] += v;
        __syncthreads();
    }
    int texcl = (threadIdx.x == 0) ? 0 : ssum[threadIdx.x - 1];
    int offbase = partial[blockIdx.x] + texcl;
#pragma unroll
    for (int k = 0; k < 8; ++k) {
        int idx = base + t0 + k;
        if (idx < NN) {
            int v = offbase + loc[k];
            row_ptr[idx] = v;
            cursor[idx]  = v;
        }
    }
    if (blockIdx.x == 0 && threadIdx.x == 0) row_ptr[NN] = NE;
}

__global__ void k_fill(const int* __restrict__ src, const int* __restrict__ dst,
                       int* __restrict__ cursor, int* __restrict__ csr) {
    int stride = gridDim.x * blockDim.x;
    for (int e = blockIdx.x * blockDim.x + threadIdx.x; e < NE; e += stride) {
        int d = dst[e];
        int p = atomicAdd(&cursor[d], 1);
        csr[p] = src[e];
    }
}

// ---------------- x split: fp32 -> hi/lo bf16 ----------------
__global__ void k_xsplit(const float* __restrict__ x, unsigned short* __restrict__ xhi,
                         unsigned short* __restrict__ xlo) {
    int idx = blockIdx.x * 256 + threadIdx.x;     // over float4s, NN*128/4 total
    float4 v = ((const float4*)x)[idx];
    unsigned int p0 = split2u(v.x), p1 = split2u(v.y), p2 = split2u(v.z), p3 = split2u(v.w);
    ushort4v h, l;
    h.x = (unsigned short)p0; l.x = (unsigned short)(p0 >> 16);
    h.y = (unsigned short)p1; l.y = (unsigned short)(p1 >> 16);
    h.z = (unsigned short)p2; l.z = (unsigned short)(p2 >> 16);
    h.w = (unsigned short)p3; l.w = (unsigned short)(p3 >> 16);
    ((ushort4v*)xhi)[idx] = h;
    ((ushort4v*)xlo)[idx] = l;
}

// ---------------- weight split: W[k][n] fp32 -> Wt_hi/Wt_lo [n][k] bf16 ----------------
struct WPack {
    const float* w[5];
    unsigned short* hi[5];
    unsigned short* lo[5];
};

__global__ void k_wsplit_all(WPack p) {
    int which = blockIdx.x >> 6;                     // 64 blocks per matrix
    int idx = (blockIdx.x & 63) * 256 + threadIdx.x; // over n*128+k
    int n = idx >> 7, k = idx & 127;
    float v = p.w[which][k * 128 + n];
    unsigned int pk = split2u(v);
    p.hi[which][idx] = (unsigned short)pk;
    p.lo[which][idx] = (unsigned short)(pk >> 16);
}

// ---------------- aggregation: u[i] = h[i] + sum_{j in N(i)} h[j]  (bf16 hi/lo world) --------
// Self row: hi+lo (exact). Neighbors: hi only (gather table 25.6MB, ~L2/L3 resident).
__global__ void k_agg_bf(const unsigned short* __restrict__ hhi, const unsigned short* __restrict__ hlo,
                         const int* __restrict__ row_ptr, const int* __restrict__ csr,
                         unsigned short* __restrict__ uhi, unsigned short* __restrict__ ulo) {
    int half = threadIdx.x >> 5;        // 0..7
    int l32  = threadIdx.x & 31;
    int node = blockIdx.x * 8 + half;
    if (node >= NN) return;
    size_t base = (size_t)node * F + l32 * 4;
    ushort4v sh = *(const ushort4v*)&hhi[base];
    ushort4v sl = *(const ushort4v*)&hlo[base];
    float a0 = bf2f(sh.x) + bf2f(sl.x);
    float a1 = bf2f(sh.y) + bf2f(sl.y);
    float a2 = bf2f(sh.z) + bf2f(sl.z);
    float a3 = bf2f(sh.w) + bf2f(sl.w);
    int s = row_ptr[node], e = row_ptr[node + 1];
    for (int p = s; p < e; ++p) {
        int j = csr[p];
        ushort4v v = *(const ushort4v*)&hhi[(size_t)j * F + l32 * 4];
        a0 += bf2f(v.x); a1 += bf2f(v.y); a2 += bf2f(v.z); a3 += bf2f(v.w);
    }
    unsigned int p0 = split2u(a0), p1 = split2u(a1), p2 = split2u(a2), p3 = split2u(a3);
    ushort4v h, l;
    h.x = (unsigned short)p0; l.x = (unsigned short)(p0 >> 16);
    h.y = (unsigned short)p1; l.y = (unsigned short)(p1 >> 16);
    h.z = (unsigned short)p2; l.z = (unsigned short)(p2 >> 16);
    h.w = (unsigned short)p3; l.w = (unsigned short)(p3 >> 16);
    *(ushort4v*)&uhi[base] = h;
    *(ushort4v*)&ulo[base] = l;
}

// ---------------- fused MLP layer ----------------
// L3==0: H = (relu(A@W1+b1))@W2 + b2, written as hi/lo bf16.
// L3==1: out = relu(A@W1+b1) @ w32 + b32, fp32 [NN].
// A in hi/lo bf16 [node][k]. W transposed+split [n][k]. 3-term split MFMA.
template <int L3>
__global__ __launch_bounds__(256, 2) void k_mlp(const unsigned short* __restrict__ Ahi,
                                                const unsigned short* __restrict__ Alo,
                                                const unsigned short* __restrict__ W1hi,
                                                const unsigned short* __restrict__ W1lo,
                                                const float* __restrict__ b1,
                                                const unsigned short* __restrict__ W2hi,
                                                const unsigned short* __restrict__ W2lo,
                                                const float* __restrict__ b2,
                                                const float* __restrict__ w32,
                                                const float* __restrict__ b32,
                                                unsigned short* __restrict__ Hhi,
                                                unsigned short* __restrict__ Hlo,
                                                float* __restrict__ out) {
    __shared__ __align__(16) unsigned short sHi[128 * 128];
    __shared__ __align__(16) unsigned short sLo[128 * 128];

    const int tid = threadIdx.x;
    const int row0 = blockIdx.x * 128;
    const int wave = tid >> 6;
    const int lane = tid & 63;
    const int m16  = lane & 15;
    const int quad = lane >> 4;

    // ---- stage A tile (bf16 hi/lo, 16B-granule XOR swizzle) ----
    {
        int r = tid >> 1;
        int cb = (tid & 1) * 64;
        int grow = row0 + r;
        const ushort8v* gh = (const ushort8v*)&Ahi[(size_t)grow * F + cb];
        const ushort8v* gl = (const ushort8v*)&Alo[(size_t)grow * F + cb];
#pragma unroll
        for (int i = 0; i < 8; ++i) {
            ushort8v vh = {}, vl = {};
            if (grow < NN) { vh = gh[i]; vl = gl[i]; }
            int c = cb + i * 8;
            int addr = r * 128 + (((c >> 3) ^ (r & 15)) << 3);
            *(ushort8v*)&sHi[addr] = vh;
            *(ushort8v*)&sLo[addr] = vl;
        }
    }
    __syncthreads();

    // ---- GEMM1 ----
    f32x4 acc[2][8] = {};
#pragma unroll
    for (int ks = 0; ks < 4; ++ks) {
        bf16x8 a_hi[2], a_lo[2];
#pragma unroll
        for (int rt = 0; rt < 2; ++rt) {
            int rowLocal = wave * 32 + rt * 16 + m16;
            int u = ks * 4 + quad;
            int aoff = rowLocal * 128 + ((u ^ m16) << 3);
            a_hi[rt] = *(const bf16x8*)&sHi[aoff];
            a_lo[rt] = *(const bf16x8*)&sLo[aoff];
        }
#pragma unroll
        for (int ct = 0; ct < 8; ++ct) {
            int widx = (ct * 16 + m16) * 128 + ks * 32 + quad * 8;
            bf16x8 bh = *(const bf16x8*)&W1hi[widx];
            bf16x8 bl = *(const bf16x8*)&W1lo[widx];
#pragma unroll
            for (int rt = 0; rt < 2; ++rt) {
                acc[rt][ct] = __builtin_amdgcn_mfma_f32_16x16x32_bf16(a_hi[rt], bh, acc[rt][ct], 0, 0, 0);
                acc[rt][ct] = __builtin_amdgcn_mfma_f32_16x16x32_bf16(a_hi[rt], bl, acc[rt][ct], 0, 0, 0);
                acc[rt][ct] = __builtin_amdgcn_mfma_f32_16x16x32_bf16(a_lo[rt], bh, acc[rt][ct], 0, 0, 0);
            }
        }
    }

    if (L3) {
        // ---- bias + relu + dot with w32, reduce across m16 lanes ----
#pragma unroll
        for (int rt = 0; rt < 2; ++rt) {
            float s[4] = {0.f, 0.f, 0.f, 0.f};
#pragma unroll
            for (int ct = 0; ct < 8; ++ct) {
                int col = ct * 16 + m16;
                float bv = b1[col];
                float wv = w32[col];
#pragma unroll
                for (int i = 0; i < 4; ++i) {
                    float v = fmaxf(acc[rt][ct][i] + bv, 0.f);
                    s[i] += v * wv;
                }
            }
#pragma unroll
            for (int i = 0; i < 4; ++i) {
#pragma unroll
                for (int mask = 1; mask < 16; mask <<= 1)
                    s[i] += __shfl_xor(s[i], mask, 64);
            }
            if (m16 == 0) {
#pragma unroll
                for (int i = 0; i < 4; ++i) {
                    int row = row0 + wave * 32 + rt * 16 + quad * 4 + i;
                    if (row < NN) out[row] = s[i] + b32[0];
                }
            }
        }
        return;
    }

    // ---- h1 = relu(acc+b1) -> hi/lo bf16 into LDS (C-layout -> A-layout round trip) ----
    __syncthreads();   // all sA reads done before overwrite
#pragma unroll
    for (int rt = 0; rt < 2; ++rt) {
#pragma unroll
        for (int ct = 0; ct < 8; ++ct) {
            int col = ct * 16 + m16;
            float bv = b1[col];
#pragma unroll
            for (int i = 0; i < 4; ++i) {
                int rowL = wave * 32 + rt * 16 + quad * 4 + i;
                float v = fmaxf(acc[rt][ct][i] + bv, 0.f);
                unsigned int pk = split2u(v);
                int addr = rowL * 128 + (((col >> 3) ^ (rowL & 15)) << 3) + (col & 7);
                sHi[addr] = (unsigned short)pk;
                sLo[addr] = (unsigned short)(pk >> 16);
            }
        }
    }
    __syncthreads();

    // ---- GEMM2 ----
    f32x4 acc2[2][8] = {};
#pragma unroll
    for (int ks = 0; ks < 4; ++ks) {
        bf16x8 a_hi[2], a_lo[2];
#pragma unroll
        for (int rt = 0; rt < 2; ++rt) {
            int rowLocal = wave * 32 + rt * 16 + m16;
            int u = ks * 4 + quad;
            int aoff = rowLocal * 128 + ((u ^ m16) << 3);
            a_hi[rt] = *(const bf16x8*)&sHi[aoff];
            a_lo[rt] = *(const bf16x8*)&sLo[aoff];
        }
#pragma unroll
        for (int ct = 0; ct < 8; ++ct) {
            int widx = (ct * 16 + m16) * 128 + ks * 32 + quad * 8;
            bf16x8 bh = *(const bf16x8*)&W2hi[widx];
            bf16x8 bl = *(const bf16x8*)&W2lo[widx];
#pragma unroll
            for (int rt = 0; rt < 2; ++rt) {
                acc2[rt][ct] = __builtin_amdgcn_mfma_f32_16x16x32_bf16(a_hi[rt], bh, acc2[rt][ct], 0, 0, 0);
                acc2[rt][ct] = __builtin_amdgcn_mfma_f32_16x16x32_bf16(a_hi[rt], bl, acc2[rt][ct], 0, 0, 0);
                acc2[rt][ct] = __builtin_amdgcn_mfma_f32_16x16x32_bf16(a_lo[rt], bh, acc2[rt][ct], 0, 0, 0);
            }
        }
    }

    // ---- epilogue: bias, split, store hi/lo bf16 ----
#pragma unroll
    for (int rt = 0; rt < 2; ++rt) {
#pragma unroll
        for (int ct = 0; ct < 8; ++ct) {
            int col = ct * 16 + m16;
            float bv = b2[col];
#pragma unroll
            for (int i = 0; i < 4; ++i) {
                int row = row0 + wave * 32 + rt * 16 + quad * 4 + i;
                if (row < NN) {
                    float v = acc2[rt][ct][i] + bv;
                    unsigned int pk = split2u(v);
                    Hhi[(size_t)row * F + col] = (unsigned short)pk;
                    Hlo[(size_t)row * F + col] = (unsigned short)(pk >> 16);
                }
            }
        }
    }
}

// ---------------- launch ----------------
static inline size_t align256(size_t x) { return (x + 255) & ~(size_t)255; }

extern "C" void kernel_launch(void* const* d_in, const int* in_sizes, int n_in,
                              void* d_out, int out_size, void* d_ws, size_t ws_size,
                              hipStream_t stream) {
    const float* x   = (const float*)d_in[0];
    const int*   ei  = (const int*)d_in[1];
    const float* w11 = (const float*)d_in[2];
    const float* b11 = (const float*)d_in[3];
    const float* w12 = (const float*)d_in[4];
    const float* b12 = (const float*)d_in[5];
    const float* w21 = (const float*)d_in[6];
    const float* b21 = (const float*)d_in[7];
    const float* w22 = (const float*)d_in[8];
    const float* b22 = (const float*)d_in[9];
    const float* w31 = (const float*)d_in[10];
    const float* b31 = (const float*)d_in[11];
    const float* w32 = (const float*)d_in[12];
    const float* b32 = (const float*)d_in[13];
    float* out = (float*)d_out;

    const int* src = ei;
    const int* dst = ei + NE;

    char* ws = (char*)d_ws;
    size_t off = 0;
    // A pair doubles as x-buffer and h-buffer; B pair is the u-buffer.
    unsigned short* Ahi = (unsigned short*)(ws + off); off += align256((size_t)NN * F * 2);
    unsigned short* Alo = (unsigned short*)(ws + off); off += align256((size_t)NN * F * 2);
    unsigned short* Bhi = (unsigned short*)(ws + off); off += align256((size_t)NN * F * 2);
    unsigned short* Blo = (unsigned short*)(ws + off); off += align256((size_t)NN * F * 2);
    int* deg     = (int*)(ws + off); off += align256((size_t)NN * 4);
    int* row_ptr = (int*)(ws + off); off += align256((size_t)(NN + 1) * 4);
    int* cursor  = (int*)(ws + off); off += align256((size_t)NN * 4);
    int* partial = (int*)(ws + off); off += align256((size_t)NB_SCAN * 4);
    int* csr     = (int*)(ws + off); off += align256((size_t)NE * 4);
    unsigned short* whi[5];
    unsigned short* wlo[5];
    for (int i = 0; i < 5; ++i) {
        whi[i] = (unsigned short*)(ws + off); off += align256((size_t)128 * 128 * 2);
        wlo[i] = (unsigned short*)(ws + off); off += align256((size_t)128 * 128 * 2);
    }
    (void)ws_size;

    // ---- weight + input splits ----
    WPack wp;
    wp.w[0] = w11; wp.w[1] = w12; wp.w[2] = w21; wp.w[3] = w22; wp.w[4] = w31;
    for (int i = 0; i < 5; ++i) { wp.hi[i] = whi[i]; wp.lo[i] = wlo[i]; }
    k_wsplit_all<<<320, 256, 0, stream>>>(wp);
    k_xsplit<<<(NN * F / 4 + 255) / 256, 256, 0, stream>>>(x, Ahi, Alo);

    // ---- CSR build ----
    (void)hipMemsetAsync(deg, 0, (size_t)NN * 4, stream);
    k_hist<<<2048, 256, 0, stream>>>(dst, deg);
    k_scan_part<<<NB_SCAN, 256, 0, stream>>>(deg, partial);
    k_scan_mid<<<1, 64, 0, stream>>>(partial);
    k_scan_final<<<NB_SCAN, 256, 0, stream>>>(deg, partial, row_ptr, cursor);
    k_fill<<<2048, 256, 0, stream>>>(src, dst, cursor, csr);

    const int aggBlocks  = (NN + 7) / 8;
    const int mlpBlocks  = (NN + 127) / 128;

    // ---- layer 1 ----
    k_agg_bf<<<aggBlocks, 256, 0, stream>>>(Ahi, Alo, row_ptr, csr, Bhi, Blo);
    k_mlp<0><<<mlpBlocks, 256, 0, stream>>>(Bhi, Blo, whi[0], wlo[0], b11, whi[1], wlo[1], b12,
                                            nullptr, nullptr, Ahi, Alo, nullptr);
    // ---- layer 2 ----
    k_agg_bf<<<aggBlocks, 256, 0, stream>>>(Ahi, Alo, row_ptr, csr, Bhi, Blo);
    k_mlp<0><<<mlpBlocks, 256, 0, stream>>>(Bhi, Blo, whi[2], wlo[2], b21, whi[3], wlo[3], b22,
                                            nullptr, nullptr, Ahi, Alo, nullptr);
    // ---- layer 3 ----
    k_agg_bf<<<aggBlocks, 256, 0, stream>>>(Ahi, Alo, row_ptr, csr, Bhi, Blo);
    k_mlp<1><<<mlpBlocks, 256, 0, stream>>>(Bhi, Blo, whi[4], wlo[4], b31, nullptr, nullptr, nullptr,
                                            w32, b32, nullptr, nullptr, out);
}

// Round 5
// 685.551 us; speedup vs baseline: 1.4542x; 1.2315x over previous
//
#include <hip/hip_runtime.h>

#define NN 100000
#define NE 1600000
#define F 128
#define SCAN_CHUNK 2048
#define NB_SCAN ((NN + SCAN_CHUNK - 1) / SCAN_CHUNK)   // 49
#define NBUCK ((NN + 255) >> 8)                         // 391 buckets of 256 nodes
#define EPB (NE / 256)                                  // 6250 edges per scatter block

typedef __bf16 bf16x8 __attribute__((ext_vector_type(8)));
typedef float  f32x4  __attribute__((ext_vector_type(4)));
typedef unsigned short ushort8v __attribute__((ext_vector_type(8)));
typedef unsigned short ushort4v __attribute__((ext_vector_type(4)));

__device__ inline float bf2f(unsigned short h) { return __uint_as_float(((unsigned int)h) << 16); }
// truncation split: v == bf2f(hi) + bf2f(lo); hi in [15:0], lo in [31:16]
__device__ inline unsigned int split2u(float v) {
    unsigned int u = __float_as_uint(v);
    unsigned int hi = u >> 16;
    float hf = __uint_as_float(u & 0xFFFF0000u);
    unsigned int lo = __float_as_uint(v - hf) >> 16;
    return hi | (lo << 16);
}

// ---------------- CSR build ----------------
__global__ void k_hist(const int* __restrict__ dst, int* __restrict__ deg) {
    int stride = gridDim.x * blockDim.x;
    for (int e = blockIdx.x * blockDim.x + threadIdx.x; e < NE; e += stride)
        atomicAdd(&deg[dst[e]], 1);
}

__global__ void k_scan_part(const int* __restrict__ deg, int* __restrict__ partial) {
    __shared__ int sdata[256];
    int base = blockIdx.x * SCAN_CHUNK;
    int sum = 0;
    for (int j = threadIdx.x; j < SCAN_CHUNK; j += 256) {
        int idx = base + j;
        sum += (idx < NN) ? deg[idx] : 0;
    }
    sdata[threadIdx.x] = sum;
    __syncthreads();
    for (int s = 128; s > 0; s >>= 1) {
        if (threadIdx.x < s) sdata[threadIdx.x] += sdata[threadIdx.x + s];
        __syncthreads();
    }
    if (threadIdx.x == 0) partial[blockIdx.x] = sdata[0];
}

__global__ void k_scan_mid(int* __restrict__ partial) {
    if (threadIdx.x == 0) {
        int acc = 0;
        for (int i = 0; i < NB_SCAN; ++i) { int v = partial[i]; partial[i] = acc; acc += v; }
    }
}

__global__ void k_scan_final(const int* __restrict__ deg, const int* __restrict__ partial,
                             int* __restrict__ row_ptr, int* __restrict__ cursor) {
    __shared__ int svals[SCAN_CHUNK];
    __shared__ int ssum[256];
    int base = blockIdx.x * SCAN_CHUNK;
    for (int j = threadIdx.x; j < SCAN_CHUNK; j += 256) {
        int idx = base + j;
        svals[j] = (idx < NN) ? deg[idx] : 0;
    }
    __syncthreads();
    int t0 = threadIdx.x * 8;
    int loc[8];
    int s = 0;
#pragma unroll
    for (int k = 0; k < 8; ++k) { loc[k] = s; s += svals[t0 + k]; }
    ssum[threadIdx.x] = s;
    __syncthreads();
    for (int off = 1; off < 256; off <<= 1) {
        int v = (threadIdx.x >= off) ? ssum[threadIdx.x - off] : 0;
        __syncthreads();
        ssum[threadIdx.x] += v;
        __syncthreads();
    }
    int texcl = (threadIdx.x == 0) ? 0 : ssum[threadIdx.x - 1];
    int offbase = partial[blockIdx.x] + texcl;
#pragma unroll
    for (int k = 0; k < 8; ++k) {
        int idx = base + t0 + k;
        if (idx < NN) {
            int v = offbase + loc[k];
            row_ptr[idx] = v;
            cursor[idx]  = v;
        }
    }
    if (blockIdx.x == 0 && threadIdx.x == 0) row_ptr[NN] = NE;
}

// bucket cursor init: bcur[b] = row_ptr[b*256]
__global__ void k_bcur(const int* __restrict__ row_ptr, int* __restrict__ bcur) {
    int t = blockIdx.x * 256 + threadIdx.x;
    if (t < NBUCK) bcur[t] = row_ptr[t << 8];
}

// Pass A: LDS counting-sort each 6250-edge chunk by bucket (dst>>8); write bucket-grouped
// contiguous runs of (src,dst) into scratch. Coalesced writes, no cross-XCD line sharing.
__global__ __launch_bounds__(256) void k_scatterA(const int* __restrict__ src,
                                                  const int* __restrict__ dst,
                                                  int* __restrict__ bcur,
                                                  uint2* __restrict__ scratch) {
    __shared__ uint2 sEdge[EPB];          // 50 KB
    __shared__ int cnt[512];
    __shared__ int scn[512];
    __shared__ int cntB[512];
    __shared__ int gbase[512];
    __shared__ int ssum[256];

    const int tid = threadIdx.x;
    const int ebase = blockIdx.x * EPB;

    // zero counters
#pragma unroll
    for (int i = tid; i < 512; i += 256) { cnt[i] = 0; cntB[i] = 0; }
    __syncthreads();

    // phase 1: histogram
    for (int i = tid; i < EPB; i += 256) {
        int b = dst[ebase + i] >> 8;
        atomicAdd(&cnt[b], 1);
    }
    __syncthreads();

    // exclusive scan over 512 entries (2 per thread + Hillis-Steele over 256 sums)
    int c0 = cnt[2 * tid], c1 = cnt[2 * tid + 1];
    ssum[tid] = c0 + c1;
    __syncthreads();
    for (int off = 1; off < 256; off <<= 1) {
        int v = (tid >= off) ? ssum[tid - off] : 0;
        __syncthreads();
        ssum[tid] += v;
        __syncthreads();
    }
    int texcl = (tid == 0) ? 0 : ssum[tid - 1];
    scn[2 * tid] = texcl;
    scn[2 * tid + 1] = texcl + c0;
    // reserve global runs (one atomic per non-empty bucket)
#pragma unroll
    for (int i = tid; i < NBUCK; i += 256) {
        int c = cnt[i];
        gbase[i] = c ? atomicAdd(&bcur[i], c) : 0;
    }
    __syncthreads();

    // phase 2: place edges into LDS bucket-grouped
    for (int i = tid; i < EPB; i += 256) {
        int s = src[ebase + i], d = dst[ebase + i];
        int b = d >> 8;
        int rank = atomicAdd(&cntB[b], 1);
        sEdge[scn[b] + rank] = make_uint2((unsigned)s, (unsigned)d);
    }
    __syncthreads();

    // phase 3: stream out; consecutive i within a bucket -> consecutive global slots
    for (int i = tid; i < EPB; i += 256) {
        uint2 ed = sEdge[i];
        int b = (int)(ed.y >> 8);
        scratch[gbase[b] + (i - scn[b])] = ed;
    }
}

// Pass B: one block per bucket; scattered csr writes confined to a ~16KB region (one XCD).
__global__ __launch_bounds__(256) void k_fillB(const int* __restrict__ row_ptr,
                                               const uint2* __restrict__ scratch,
                                               int* __restrict__ cursor,
                                               int* __restrict__ csr) {
    int b = blockIdx.x;
    int s = row_ptr[b << 8];
    int endNode = (b + 1) << 8; if (endNode > NN) endNode = NN;
    int e = row_ptr[endNode];
    for (int i = s + threadIdx.x; i < e; i += 256) {
        uint2 ed = scratch[i];
        int p = atomicAdd(&cursor[ed.y], 1);
        csr[p] = (int)ed.x;
    }
}

// ---------------- x split: fp32 -> hi/lo bf16 ----------------
__global__ void k_xsplit(const float* __restrict__ x, unsigned short* __restrict__ xhi,
                         unsigned short* __restrict__ xlo) {
    int idx = blockIdx.x * 256 + threadIdx.x;     // over float4s, NN*128/4 total
    float4 v = ((const float4*)x)[idx];
    unsigned int p0 = split2u(v.x), p1 = split2u(v.y), p2 = split2u(v.z), p3 = split2u(v.w);
    ushort4v h, l;
    h.x = (unsigned short)p0; l.x = (unsigned short)(p0 >> 16);
    h.y = (unsigned short)p1; l.y = (unsigned short)(p1 >> 16);
    h.z = (unsigned short)p2; l.z = (unsigned short)(p2 >> 16);
    h.w = (unsigned short)p3; l.w = (unsigned short)(p3 >> 16);
    ((ushort4v*)xhi)[idx] = h;
    ((ushort4v*)xlo)[idx] = l;
}

// ---------------- weight split: W[k][n] fp32 -> Wt_hi/Wt_lo [n][k] bf16 ----------------
struct WPack {
    const float* w[5];
    unsigned short* hi[5];
    unsigned short* lo[5];
};

__global__ void k_wsplit_all(WPack p) {
    int which = blockIdx.x >> 6;                     // 64 blocks per matrix
    int idx = (blockIdx.x & 63) * 256 + threadIdx.x; // over n*128+k
    int n = idx >> 7, k = idx & 127;
    float v = p.w[which][k * 128 + n];
    unsigned int pk = split2u(v);
    p.hi[which][idx] = (unsigned short)pk;
    p.lo[which][idx] = (unsigned short)(pk >> 16);
}

// ---------------- aggregation: u[i] = h[i] + sum_{j in N(i)} h[j]  (bf16 hi/lo world) --------
// 4-way unrolled gather: 4 independent neighbor-row loads in flight per iteration.
__global__ void k_agg_bf(const unsigned short* __restrict__ hhi, const unsigned short* __restrict__ hlo,
                         const int* __restrict__ row_ptr, const int* __restrict__ csr,
                         unsigned short* __restrict__ uhi, unsigned short* __restrict__ ulo) {
    int half = threadIdx.x >> 5;        // 0..7
    int l32  = threadIdx.x & 31;
    int node = blockIdx.x * 8 + half;
    if (node >= NN) return;
    size_t base = (size_t)node * F + l32 * 4;
    ushort4v sh = *(const ushort4v*)&hhi[base];
    ushort4v sl = *(const ushort4v*)&hlo[base];
    float a0 = bf2f(sh.x) + bf2f(sl.x);
    float a1 = bf2f(sh.y) + bf2f(sl.y);
    float a2 = bf2f(sh.z) + bf2f(sl.z);
    float a3 = bf2f(sh.w) + bf2f(sl.w);
    int s = row_ptr[node], e = row_ptr[node + 1];
    int lofs = l32 * 4;
    int p = s;
    for (; p + 4 <= e; p += 4) {
        int j0 = csr[p], j1 = csr[p + 1], j2 = csr[p + 2], j3 = csr[p + 3];
        ushort4v v0 = *(const ushort4v*)&hhi[(size_t)j0 * F + lofs];
        ushort4v v1 = *(const ushort4v*)&hhi[(size_t)j1 * F + lofs];
        ushort4v v2 = *(const ushort4v*)&hhi[(size_t)j2 * F + lofs];
        ushort4v v3 = *(const ushort4v*)&hhi[(size_t)j3 * F + lofs];
        a0 += bf2f(v0.x) + bf2f(v1.x) + bf2f(v2.x) + bf2f(v3.x);
        a1 += bf2f(v0.y) + bf2f(v1.y) + bf2f(v2.y) + bf2f(v3.y);
        a2 += bf2f(v0.z) + bf2f(v1.z) + bf2f(v2.z) + bf2f(v3.z);
        a3 += bf2f(v0.w) + bf2f(v1.w) + bf2f(v2.w) + bf2f(v3.w);
    }
    if (p + 2 <= e) {
        int j0 = csr[p], j1 = csr[p + 1];
        ushort4v v0 = *(const ushort4v*)&hhi[(size_t)j0 * F + lofs];
        ushort4v v1 = *(const ushort4v*)&hhi[(size_t)j1 * F + lofs];
        a0 += bf2f(v0.x) + bf2f(v1.x);
        a1 += bf2f(v0.y) + bf2f(v1.y);
        a2 += bf2f(v0.z) + bf2f(v1.z);
        a3 += bf2f(v0.w) + bf2f(v1.w);
        p += 2;
    }
    if (p < e) {
        int j0 = csr[p];
        ushort4v v0 = *(const ushort4v*)&hhi[(size_t)j0 * F + lofs];
        a0 += bf2f(v0.x); a1 += bf2f(v0.y); a2 += bf2f(v0.z); a3 += bf2f(v0.w);
    }
    unsigned int p0 = split2u(a0), p1 = split2u(a1), p2 = split2u(a2), p3 = split2u(a3);
    ushort4v h, l;
    h.x = (unsigned short)p0; l.x = (unsigned short)(p0 >> 16);
    h.y = (unsigned short)p1; l.y = (unsigned short)(p1 >> 16);
    h.z = (unsigned short)p2; l.z = (unsigned short)(p2 >> 16);
    h.w = (unsigned short)p3; l.w = (unsigned short)(p3 >> 16);
    *(ushort4v*)&uhi[base] = h;
    *(ushort4v*)&ulo[base] = l;
}

// ---------------- fused MLP layer ----------------
// L3==0: H = (relu(A@W1+b1))@W2 + b2, written as hi/lo bf16.
// L3==1: out = relu(A@W1+b1) @ w32 + b32, fp32 [NN].
template <int L3>
__global__ __launch_bounds__(256, 2) void k_mlp(const unsigned short* __restrict__ Ahi,
                                                const unsigned short* __restrict__ Alo,
                                                const unsigned short* __restrict__ W1hi,
                                                const unsigned short* __restrict__ W1lo,
                                                const float* __restrict__ b1,
                                                const unsigned short* __restrict__ W2hi,
                                                const unsigned short* __restrict__ W2lo,
                                                const float* __restrict__ b2,
                                                const float* __restrict__ w32,
                                                const float* __restrict__ b32,
                                                unsigned short* __restrict__ Hhi,
                                                unsigned short* __restrict__ Hlo,
                                                float* __restrict__ out) {
    __shared__ __align__(16) unsigned short sHi[128 * 128];
    __shared__ __align__(16) unsigned short sLo[128 * 128];

    const int tid = threadIdx.x;
    const int row0 = blockIdx.x * 128;
    const int wave = tid >> 6;
    const int lane = tid & 63;
    const int m16  = lane & 15;
    const int quad = lane >> 4;

    // ---- stage A tile (bf16 hi/lo, 16B-granule XOR swizzle) ----
    {
        int r = tid >> 1;
        int cb = (tid & 1) * 64;
        int grow = row0 + r;
        const ushort8v* gh = (const ushort8v*)&Ahi[(size_t)grow * F + cb];
        const ushort8v* gl = (const ushort8v*)&Alo[(size_t)grow * F + cb];
#pragma unroll
        for (int i = 0; i < 8; ++i) {
            ushort8v vh = {}, vl = {};
            if (grow < NN) { vh = gh[i]; vl = gl[i]; }
            int c = cb + i * 8;
            int addr = r * 128 + (((c >> 3) ^ (r & 15)) << 3);
            *(ushort8v*)&sHi[addr] = vh;
            *(ushort8v*)&sLo[addr] = vl;
        }
    }
    __syncthreads();

    // ---- GEMM1 ----
    f32x4 acc[2][8] = {};
#pragma unroll
    for (int ks = 0; ks < 4; ++ks) {
        bf16x8 a_hi[2], a_lo[2];
#pragma unroll
        for (int rt = 0; rt < 2; ++rt) {
            int rowLocal = wave * 32 + rt * 16 + m16;
            int u = ks * 4 + quad;
            int aoff = rowLocal * 128 + ((u ^ m16) << 3);
            a_hi[rt] = *(const bf16x8*)&sHi[aoff];
            a_lo[rt] = *(const bf16x8*)&sLo[aoff];
        }
#pragma unroll
        for (int ct = 0; ct < 8; ++ct) {
            int widx = (ct * 16 + m16) * 128 + ks * 32 + quad * 8;
            bf16x8 bh = *(const bf16x8*)&W1hi[widx];
            bf16x8 bl = *(const bf16x8*)&W1lo[widx];
#pragma unroll
            for (int rt = 0; rt < 2; ++rt) {
                acc[rt][ct] = __builtin_amdgcn_mfma_f32_16x16x32_bf16(a_hi[rt], bh, acc[rt][ct], 0, 0, 0);
                acc[rt][ct] = __builtin_amdgcn_mfma_f32_16x16x32_bf16(a_hi[rt], bl, acc[rt][ct], 0, 0, 0);
                acc[rt][ct] = __builtin_amdgcn_mfma_f32_16x16x32_bf16(a_lo[rt], bh, acc[rt][ct], 0, 0, 0);
            }
        }
    }

    if (L3) {
#pragma unroll
        for (int rt = 0; rt < 2; ++rt) {
            float s[4] = {0.f, 0.f, 0.f, 0.f};
#pragma unroll
            for (int ct = 0; ct < 8; ++ct) {
                int col = ct * 16 + m16;
                float bv = b1[col];
                float wv = w32[col];
#pragma unroll
                for (int i = 0; i < 4; ++i) {
                    float v = fmaxf(acc[rt][ct][i] + bv, 0.f);
                    s[i] += v * wv;
                }
            }
#pragma unroll
            for (int i = 0; i < 4; ++i) {
#pragma unroll
                for (int mask = 1; mask < 16; mask <<= 1)
                    s[i] += __shfl_xor(s[i], mask, 64);
            }
            if (m16 == 0) {
#pragma unroll
                for (int i = 0; i < 4; ++i) {
                    int row = row0 + wave * 32 + rt * 16 + quad * 4 + i;
                    if (row < NN) out[row] = s[i] + b32[0];
                }
            }
        }
        return;
    }

    // ---- h1 = relu(acc+b1) -> hi/lo bf16 into LDS (C-layout -> A-layout round trip) ----
    __syncthreads();
#pragma unroll
    for (int rt = 0; rt < 2; ++rt) {
#pragma unroll
        for (int ct = 0; ct < 8; ++ct) {
            int col = ct * 16 + m16;
            float bv = b1[col];
#pragma unroll
            for (int i = 0; i < 4; ++i) {
                int rowL = wave * 32 + rt * 16 + quad * 4 + i;
                float v = fmaxf(acc[rt][ct][i] + bv, 0.f);
                unsigned int pk = split2u(v);
                int addr = rowL * 128 + (((col >> 3) ^ (rowL & 15)) << 3) + (col & 7);
                sHi[addr] = (unsigned short)pk;
                sLo[addr] = (unsigned short)(pk >> 16);
            }
        }
    }
    __syncthreads();

    // ---- GEMM2 ----
    f32x4 acc2[2][8] = {};
#pragma unroll
    for (int ks = 0; ks < 4; ++ks) {
        bf16x8 a_hi[2], a_lo[2];
#pragma unroll
        for (int rt = 0; rt < 2; ++rt) {
            int rowLocal = wave * 32 + rt * 16 + m16;
            int u = ks * 4 + quad;
            int aoff = rowLocal * 128 + ((u ^ m16) << 3);
            a_hi[rt] = *(const bf16x8*)&sHi[aoff];
            a_lo[rt] = *(const bf16x8*)&sLo[aoff];
        }
#pragma unroll
        for (int ct = 0; ct < 8; ++ct) {
            int widx = (ct * 16 + m16) * 128 + ks * 32 + quad * 8;
            bf16x8 bh = *(const bf16x8*)&W2hi[widx];
            bf16x8 bl = *(const bf16x8*)&W2lo[widx];
#pragma unroll
            for (int rt = 0; rt < 2; ++rt) {
                acc2[rt][ct] = __builtin_amdgcn_mfma_f32_16x16x32_bf16(a_hi[rt], bh, acc2[rt][ct], 0, 0, 0);
                acc2[rt][ct] = __builtin_amdgcn_mfma_f32_16x16x32_bf16(a_hi[rt], bl, acc2[rt][ct], 0, 0, 0);
                acc2[rt][ct] = __builtin_amdgcn_mfma_f32_16x16x32_bf16(a_lo[rt], bh, acc2[rt][ct], 0, 0, 0);
            }
        }
    }

    // ---- epilogue: bias, split, store hi/lo bf16 ----
#pragma unroll
    for (int rt = 0; rt < 2; ++rt) {
#pragma unroll
        for (int ct = 0; ct < 8; ++ct) {
            int col = ct * 16 + m16;
            float bv = b2[col];
#pragma unroll
            for (int i = 0; i < 4; ++i) {
                int row = row0 + wave * 32 + rt * 16 + quad * 4 + i;
                if (row < NN) {
                    float v = acc2[rt][ct][i] + bv;
                    unsigned int pk = split2u(v);
                    Hhi[(size_t)row * F + col] = (unsigned short)pk;
                    Hlo[(size_t)row * F + col] = (unsigned short)(pk >> 16);
                }
            }
        }
    }
}

// ---------------- launch ----------------
static inline size_t align256(size_t x) { return (x + 255) & ~(size_t)255; }

extern "C" void kernel_launch(void* const* d_in, const int* in_sizes, int n_in,
                              void* d_out, int out_size, void* d_ws, size_t ws_size,
                              hipStream_t stream) {
    const float* x   = (const float*)d_in[0];
    const int*   ei  = (const int*)d_in[1];
    const float* w11 = (const float*)d_in[2];
    const float* b11 = (const float*)d_in[3];
    const float* w12 = (const float*)d_in[4];
    const float* b12 = (const float*)d_in[5];
    const float* w21 = (const float*)d_in[6];
    const float* b21 = (const float*)d_in[7];
    const float* w22 = (const float*)d_in[8];
    const float* b22 = (const float*)d_in[9];
    const float* w31 = (const float*)d_in[10];
    const float* b31 = (const float*)d_in[11];
    const float* w32 = (const float*)d_in[12];
    const float* b32 = (const float*)d_in[13];
    float* out = (float*)d_out;

    const int* src = ei;
    const int* dst = ei + NE;

    char* ws = (char*)d_ws;
    size_t off = 0;
    unsigned short* Ahi = (unsigned short*)(ws + off); off += align256((size_t)NN * F * 2);
    unsigned short* Alo = (unsigned short*)(ws + off); off += align256((size_t)NN * F * 2);
    unsigned short* Bhi = (unsigned short*)(ws + off); off += align256((size_t)NN * F * 2);
    unsigned short* Blo = (unsigned short*)(ws + off); off += align256((size_t)NN * F * 2);
    int* deg     = (int*)(ws + off); off += align256((size_t)NN * 4);
    int* row_ptr = (int*)(ws + off); off += align256((size_t)(NN + 1) * 4);
    int* cursor  = (int*)(ws + off); off += align256((size_t)NN * 4);
    int* partial = (int*)(ws + off); off += align256((size_t)NB_SCAN * 4);
    int* bcur    = (int*)(ws + off); off += align256((size_t)NBUCK * 4);
    int* csr     = (int*)(ws + off); off += align256((size_t)NE * 4);
    uint2* scratch = (uint2*)(ws + off); off += align256((size_t)NE * 8);
    unsigned short* whi[5];
    unsigned short* wlo[5];
    for (int i = 0; i < 5; ++i) {
        whi[i] = (unsigned short*)(ws + off); off += align256((size_t)128 * 128 * 2);
        wlo[i] = (unsigned short*)(ws + off); off += align256((size_t)128 * 128 * 2);
    }
    (void)ws_size;

    // ---- weight + input splits ----
    WPack wp;
    wp.w[0] = w11; wp.w[1] = w12; wp.w[2] = w21; wp.w[3] = w22; wp.w[4] = w31;
    for (int i = 0; i < 5; ++i) { wp.hi[i] = whi[i]; wp.lo[i] = wlo[i]; }
    k_wsplit_all<<<320, 256, 0, stream>>>(wp);
    k_xsplit<<<(NN * F / 4 + 255) / 256, 256, 0, stream>>>(x, Ahi, Alo);

    // ---- CSR build ----
    (void)hipMemsetAsync(deg, 0, (size_t)NN * 4, stream);
    k_hist<<<2048, 256, 0, stream>>>(dst, deg);
    k_scan_part<<<NB_SCAN, 256, 0, stream>>>(deg, partial);
    k_scan_mid<<<1, 64, 0, stream>>>(partial);
    k_scan_final<<<NB_SCAN, 256, 0, stream>>>(deg, partial, row_ptr, cursor);
    k_bcur<<<(NBUCK + 255) / 256, 256, 0, stream>>>(row_ptr, bcur);
    k_scatterA<<<256, 256, 0, stream>>>(src, dst, bcur, scratch);
    k_fillB<<<NBUCK, 256, 0, stream>>>(row_ptr, scratch, cursor, csr);

    const int aggBlocks  = (NN + 7) / 8;
    const int mlpBlocks  = (NN + 127) / 128;

    // ---- layer 1 ----
    k_agg_bf<<<aggBlocks, 256, 0, stream>>>(Ahi, Alo, row_ptr, csr, Bhi, Blo);
    k_mlp<0><<<mlpBlocks, 256, 0, stream>>>(Bhi, Blo, whi[0], wlo[0], b11, whi[1], wlo[1], b12,
                                            nullptr, nullptr, Ahi, Alo, nullptr);
    // ---- layer 2 ----
    k_agg_bf<<<aggBlocks, 256, 0, stream>>>(Ahi, Alo, row_ptr, csr, Bhi, Blo);
    k_mlp<0><<<mlpBlocks, 256, 0, stream>>>(Bhi, Blo, whi[2], wlo[2], b21, whi[3], wlo[3], b22,
                                            nullptr, nullptr, Ahi, Alo, nullptr);
    // ---- layer 3 ----
    k_agg_bf<<<aggBlocks, 256, 0, stream>>>(Ahi, Alo, row_ptr, csr, Bhi, Blo);
    k_mlp<1><<<mlpBlocks, 256, 0, stream>>>(Bhi, Blo, whi[4], wlo[4], b31, nullptr, nullptr, nullptr,
                                            w32, b32, nullptr, nullptr, out);
}

// Round 6
// 634.144 us; speedup vs baseline: 1.5721x; 1.0811x over previous
//
#include <hip/hip_runtime.h>

#define NN 100000
#define NE 1600000
#define F 128
#define SCAN_CHUNK 2048
#define NB_SCAN ((NN + SCAN_CHUNK - 1) / SCAN_CHUNK)   // 49
#define NBUCK ((NN + 255) >> 8)                         // 391 buckets of 256 nodes
#define EPB (NE / 256)                                  // 6250 edges per scatter block

typedef __bf16 bf16x8 __attribute__((ext_vector_type(8)));
typedef float  f32x4  __attribute__((ext_vector_type(4)));
typedef unsigned short ushort8v __attribute__((ext_vector_type(8)));
typedef unsigned short ushort4v __attribute__((ext_vector_type(4)));

__device__ inline float bf2f(unsigned short h) { return __uint_as_float(((unsigned int)h) << 16); }
// round-to-nearest-even bf16
__device__ inline unsigned short f2bf_rn(float f) {
    unsigned int u = __float_as_uint(f);
    return (unsigned short)((u + 0x7FFFu + ((u >> 16) & 1u)) >> 16);
}

// ---------------- CSR build ----------------
__global__ void k_hist(const int* __restrict__ dst, int* __restrict__ deg) {
    int stride = gridDim.x * blockDim.x;
    for (int e = blockIdx.x * blockDim.x + threadIdx.x; e < NE; e += stride)
        atomicAdd(&deg[dst[e]], 1);
}

__global__ void k_scan_part(const int* __restrict__ deg, int* __restrict__ partial) {
    __shared__ int sdata[256];
    int base = blockIdx.x * SCAN_CHUNK;
    int sum = 0;
    for (int j = threadIdx.x; j < SCAN_CHUNK; j += 256) {
        int idx = base + j;
        sum += (idx < NN) ? deg[idx] : 0;
    }
    sdata[threadIdx.x] = sum;
    __syncthreads();
    for (int s = 128; s > 0; s >>= 1) {
        if (threadIdx.x < s) sdata[threadIdx.x] += sdata[threadIdx.x + s];
        __syncthreads();
    }
    if (threadIdx.x == 0) partial[blockIdx.x] = sdata[0];
}

__global__ void k_scan_mid(int* __restrict__ partial) {
    if (threadIdx.x == 0) {
        int acc = 0;
        for (int i = 0; i < NB_SCAN; ++i) { int v = partial[i]; partial[i] = acc; acc += v; }
    }
}

__global__ void k_scan_final(const int* __restrict__ deg, const int* __restrict__ partial,
                             int* __restrict__ row_ptr, int* __restrict__ cursor) {
    __shared__ int svals[SCAN_CHUNK];
    __shared__ int ssum[256];
    int base = blockIdx.x * SCAN_CHUNK;
    for (int j = threadIdx.x; j < SCAN_CHUNK; j += 256) {
        int idx = base + j;
        svals[j] = (idx < NN) ? deg[idx] : 0;
    }
    __syncthreads();
    int t0 = threadIdx.x * 8;
    int loc[8];
    int s = 0;
#pragma unroll
    for (int k = 0; k < 8; ++k) { loc[k] = s; s += svals[t0 + k]; }
    ssum[threadIdx.x] = s;
    __syncthreads();
    for (int off = 1; off < 256; off <<= 1) {
        int v = (threadIdx.x >= off) ? ssum[threadIdx.x - off] : 0;
        __syncthreads();
        ssum[threadIdx.x] += v;
        __syncthreads();
    }
    int texcl = (threadIdx.x == 0) ? 0 : ssum[threadIdx.x - 1];
    int offbase = partial[blockIdx.x] + texcl;
#pragma unroll
    for (int k = 0; k < 8; ++k) {
        int idx = base + t0 + k;
        if (idx < NN) {
            int v = offbase + loc[k];
            row_ptr[idx] = v;
            cursor[idx]  = v;
        }
    }
    if (blockIdx.x == 0 && threadIdx.x == 0) row_ptr[NN] = NE;
}

__global__ void k_bcur(const int* __restrict__ row_ptr, int* __restrict__ bcur) {
    int t = blockIdx.x * 256 + threadIdx.x;
    if (t < NBUCK) bcur[t] = row_ptr[t << 8];
}

// Pass A: LDS counting-sort each 6250-edge chunk by bucket (dst>>8); bucket-grouped runs out.
__global__ __launch_bounds__(256) void k_scatterA(const int* __restrict__ src,
                                                  const int* __restrict__ dst,
                                                  int* __restrict__ bcur,
                                                  uint2* __restrict__ scratch) {
    __shared__ uint2 sEdge[EPB];          // 50 KB
    __shared__ int cnt[512];
    __shared__ int scn[512];
    __shared__ int cntB[512];
    __shared__ int gbase[512];
    __shared__ int ssum[256];

    const int tid = threadIdx.x;
    const int ebase = blockIdx.x * EPB;

#pragma unroll
    for (int i = tid; i < 512; i += 256) { cnt[i] = 0; cntB[i] = 0; }
    __syncthreads();

    for (int i = tid; i < EPB; i += 256) {
        int b = dst[ebase + i] >> 8;
        atomicAdd(&cnt[b], 1);
    }
    __syncthreads();

    int c0 = cnt[2 * tid], c1 = cnt[2 * tid + 1];
    ssum[tid] = c0 + c1;
    __syncthreads();
    for (int off = 1; off < 256; off <<= 1) {
        int v = (tid >= off) ? ssum[tid - off] : 0;
        __syncthreads();
        ssum[tid] += v;
        __syncthreads();
    }
    int texcl = (tid == 0) ? 0 : ssum[tid - 1];
    scn[2 * tid] = texcl;
    scn[2 * tid + 1] = texcl + c0;
#pragma unroll
    for (int i = tid; i < NBUCK; i += 256) {
        int c = cnt[i];
        gbase[i] = c ? atomicAdd(&bcur[i], c) : 0;
    }
    __syncthreads();

    for (int i = tid; i < EPB; i += 256) {
        int s = src[ebase + i], d = dst[ebase + i];
        int b = d >> 8;
        int rank = atomicAdd(&cntB[b], 1);
        sEdge[scn[b] + rank] = make_uint2((unsigned)s, (unsigned)d);
    }
    __syncthreads();

    for (int i = tid; i < EPB; i += 256) {
        uint2 ed = sEdge[i];
        int b = (int)(ed.y >> 8);
        scratch[gbase[b] + (i - scn[b])] = ed;
    }
}

// Pass B: one block per bucket; scattered csr writes confined to ~16KB region.
__global__ __launch_bounds__(256) void k_fillB(const int* __restrict__ row_ptr,
                                               const uint2* __restrict__ scratch,
                                               int* __restrict__ cursor,
                                               int* __restrict__ csr) {
    int b = blockIdx.x;
    int s = row_ptr[b << 8];
    int endNode = (b + 1) << 8; if (endNode > NN) endNode = NN;
    int e = row_ptr[endNode];
    for (int i = s + threadIdx.x; i < e; i += 256) {
        uint2 ed = scratch[i];
        int p = atomicAdd(&cursor[ed.y], 1);
        csr[p] = (int)ed.x;
    }
}

// ---------------- x -> bf16 (RTN) ----------------
__global__ void k_x2bf(const float* __restrict__ x, unsigned short* __restrict__ xb) {
    int idx = blockIdx.x * 256 + threadIdx.x;     // over float4s, NN*128/4 total
    float4 v = ((const float4*)x)[idx];
    ushort4v h;
    h.x = f2bf_rn(v.x);
    h.y = f2bf_rn(v.y);
    h.z = f2bf_rn(v.z);
    h.w = f2bf_rn(v.w);
    ((ushort4v*)xb)[idx] = h;
}

// ---------------- weight split: W[k][n] fp32 -> Wt_hi/Wt_lo [n][k] bf16 (RTN pair) --------
struct WPack {
    const float* w[5];
    unsigned short* hi[5];
    unsigned short* lo[5];
};

__global__ void k_wsplit_all(WPack p) {
    int which = blockIdx.x >> 6;
    int idx = (blockIdx.x & 63) * 256 + threadIdx.x; // over n*128+k
    int n = idx >> 7, k = idx & 127;
    float v = p.w[which][k * 128 + n];
    unsigned short h = f2bf_rn(v);
    unsigned short l = f2bf_rn(v - bf2f(h));
    p.hi[which][idx] = h;
    p.lo[which][idx] = l;
}

// ---------------- aggregation: u[i] = h[i] + sum_{j in N(i)} h[j]  (bf16 world) ----------
__global__ void k_agg_bf(const unsigned short* __restrict__ h, const int* __restrict__ row_ptr,
                         const int* __restrict__ csr, unsigned short* __restrict__ u) {
    int half = threadIdx.x >> 5;        // 0..7
    int l32  = threadIdx.x & 31;
    int node = blockIdx.x * 8 + half;
    if (node >= NN) return;
    size_t base = (size_t)node * F + l32 * 4;
    ushort4v sh = *(const ushort4v*)&h[base];
    float a0 = bf2f(sh.x), a1 = bf2f(sh.y), a2 = bf2f(sh.z), a3 = bf2f(sh.w);
    int s = row_ptr[node], e = row_ptr[node + 1];
    int lofs = l32 * 4;
    int p = s;
    for (; p + 4 <= e; p += 4) {
        int j0 = csr[p], j1 = csr[p + 1], j2 = csr[p + 2], j3 = csr[p + 3];
        ushort4v v0 = *(const ushort4v*)&h[(size_t)j0 * F + lofs];
        ushort4v v1 = *(const ushort4v*)&h[(size_t)j1 * F + lofs];
        ushort4v v2 = *(const ushort4v*)&h[(size_t)j2 * F + lofs];
        ushort4v v3 = *(const ushort4v*)&h[(size_t)j3 * F + lofs];
        a0 += bf2f(v0.x) + bf2f(v1.x) + bf2f(v2.x) + bf2f(v3.x);
        a1 += bf2f(v0.y) + bf2f(v1.y) + bf2f(v2.y) + bf2f(v3.y);
        a2 += bf2f(v0.z) + bf2f(v1.z) + bf2f(v2.z) + bf2f(v3.z);
        a3 += bf2f(v0.w) + bf2f(v1.w) + bf2f(v2.w) + bf2f(v3.w);
    }
    if (p + 2 <= e) {
        int j0 = csr[p], j1 = csr[p + 1];
        ushort4v v0 = *(const ushort4v*)&h[(size_t)j0 * F + lofs];
        ushort4v v1 = *(const ushort4v*)&h[(size_t)j1 * F + lofs];
        a0 += bf2f(v0.x) + bf2f(v1.x);
        a1 += bf2f(v0.y) + bf2f(v1.y);
        a2 += bf2f(v0.z) + bf2f(v1.z);
        a3 += bf2f(v0.w) + bf2f(v1.w);
        p += 2;
    }
    if (p < e) {
        int j0 = csr[p];
        ushort4v v0 = *(const ushort4v*)&h[(size_t)j0 * F + lofs];
        a0 += bf2f(v0.x); a1 += bf2f(v0.y); a2 += bf2f(v0.z); a3 += bf2f(v0.w);
    }
    ushort4v o;
    o.x = f2bf_rn(a0); o.y = f2bf_rn(a1); o.z = f2bf_rn(a2); o.w = f2bf_rn(a3);
    *(ushort4v*)&u[base] = o;
}

// ---------------- fused MLP layer (bf16 activations, split weights) ----------------
// L3==0: H = (relu(A@W1+b1))@W2 + b2, written bf16.
// L3==1: out = relu(A@W1+b1) @ w32 + b32, fp32 [NN].
// A bf16 [node][k]; W hi/lo [n][k]; 2-term MFMA (A*Wh + A*Wl) keeps weights fp32-exact.
template <int L3>
__global__ __launch_bounds__(256, 4) void k_mlp(const unsigned short* __restrict__ A,
                                                const unsigned short* __restrict__ W1hi,
                                                const unsigned short* __restrict__ W1lo,
                                                const float* __restrict__ b1,
                                                const unsigned short* __restrict__ W2hi,
                                                const unsigned short* __restrict__ W2lo,
                                                const float* __restrict__ b2,
                                                const float* __restrict__ w32,
                                                const float* __restrict__ b32,
                                                unsigned short* __restrict__ H,
                                                float* __restrict__ out) {
    __shared__ __align__(16) unsigned short sA[128 * 128];   // 32 KB

    const int tid = threadIdx.x;
    const int row0 = blockIdx.x * 128;
    const int wave = tid >> 6;
    const int lane = tid & 63;
    const int m16  = lane & 15;
    const int quad = lane >> 4;

    // ---- stage A tile: lane-contiguous global reads, XOR-swizzled LDS writes ----
    // tile = contiguous 32 KB at A + row0*128; granule = 8 u16 (16 B); 16 granules/row.
    {
        const ushort8v* g = (const ushort8v*)(A + (size_t)row0 * F);
#pragma unroll
        for (int i = 0; i < 8; ++i) {
            int fg = i * 256 + tid;              // 0..2047
            int r = fg >> 4, u = fg & 15;
            ushort8v v = {};
            if (row0 + r < NN) v = g[fg];
            *(ushort8v*)&sA[r * 128 + ((u ^ (r & 15)) << 3)] = v;
        }
    }
    __syncthreads();

    // ---- GEMM1 ----
    f32x4 acc[2][8] = {};
#pragma unroll
    for (int ks = 0; ks < 4; ++ks) {
        bf16x8 a[2];
#pragma unroll
        for (int rt = 0; rt < 2; ++rt) {
            int rowL = wave * 32 + rt * 16 + m16;
            int u = ks * 4 + quad;
            a[rt] = *(const bf16x8*)&sA[rowL * 128 + ((u ^ (rowL & 15)) << 3)];
        }
#pragma unroll
        for (int ct = 0; ct < 8; ++ct) {
            int widx = (ct * 16 + m16) * 128 + ks * 32 + quad * 8;
            bf16x8 bh = *(const bf16x8*)&W1hi[widx];
            bf16x8 bl = *(const bf16x8*)&W1lo[widx];
#pragma unroll
            for (int rt = 0; rt < 2; ++rt) {
                acc[rt][ct] = __builtin_amdgcn_mfma_f32_16x16x32_bf16(a[rt], bh, acc[rt][ct], 0, 0, 0);
                acc[rt][ct] = __builtin_amdgcn_mfma_f32_16x16x32_bf16(a[rt], bl, acc[rt][ct], 0, 0, 0);
            }
        }
    }

    if (L3) {
#pragma unroll
        for (int rt = 0; rt < 2; ++rt) {
            float s[4] = {0.f, 0.f, 0.f, 0.f};
#pragma unroll
            for (int ct = 0; ct < 8; ++ct) {
                int col = ct * 16 + m16;
                float bv = b1[col];
                float wv = w32[col];
#pragma unroll
                for (int i = 0; i < 4; ++i) {
                    float v = fmaxf(acc[rt][ct][i] + bv, 0.f);
                    s[i] += v * wv;
                }
            }
#pragma unroll
            for (int i = 0; i < 4; ++i) {
#pragma unroll
                for (int mask = 1; mask < 16; mask <<= 1)
                    s[i] += __shfl_xor(s[i], mask, 64);
            }
            if (m16 == 0) {
#pragma unroll
                for (int i = 0; i < 4; ++i) {
                    int row = row0 + wave * 32 + rt * 16 + quad * 4 + i;
                    if (row < NN) out[row] = s[i] + b32[0];
                }
            }
        }
        return;
    }

    // ---- h1 = relu(acc+b1) -> bf16 into LDS (C-layout -> A-layout) ----
    __syncthreads();
#pragma unroll
    for (int rt = 0; rt < 2; ++rt) {
#pragma unroll
        for (int ct = 0; ct < 8; ++ct) {
            int col = ct * 16 + m16;
            float bv = b1[col];
#pragma unroll
            for (int i = 0; i < 4; ++i) {
                int rowL = wave * 32 + rt * 16 + quad * 4 + i;
                float v = fmaxf(acc[rt][ct][i] + bv, 0.f);
                sA[rowL * 128 + (((col >> 3) ^ (rowL & 15)) << 3) + (col & 7)] = f2bf_rn(v);
            }
        }
    }
    __syncthreads();

    // ---- GEMM2 ----
    f32x4 acc2[2][8] = {};
#pragma unroll
    for (int ks = 0; ks < 4; ++ks) {
        bf16x8 a[2];
#pragma unroll
        for (int rt = 0; rt < 2; ++rt) {
            int rowL = wave * 32 + rt * 16 + m16;
            int u = ks * 4 + quad;
            a[rt] = *(const bf16x8*)&sA[rowL * 128 + ((u ^ (rowL & 15)) << 3)];
        }
#pragma unroll
        for (int ct = 0; ct < 8; ++ct) {
            int widx = (ct * 16 + m16) * 128 + ks * 32 + quad * 8;
            bf16x8 bh = *(const bf16x8*)&W2hi[widx];
            bf16x8 bl = *(const bf16x8*)&W2lo[widx];
#pragma unroll
            for (int rt = 0; rt < 2; ++rt) {
                acc2[rt][ct] = __builtin_amdgcn_mfma_f32_16x16x32_bf16(a[rt], bh, acc2[rt][ct], 0, 0, 0);
                acc2[rt][ct] = __builtin_amdgcn_mfma_f32_16x16x32_bf16(a[rt], bl, acc2[rt][ct], 0, 0, 0);
            }
        }
    }

    // ---- epilogue: bias -> bf16 -> LDS -> coalesced store ----
    __syncthreads();
#pragma unroll
    for (int rt = 0; rt < 2; ++rt) {
#pragma unroll
        for (int ct = 0; ct < 8; ++ct) {
            int col = ct * 16 + m16;
            float bv = b2[col];
#pragma unroll
            for (int i = 0; i < 4; ++i) {
                int rowL = wave * 32 + rt * 16 + quad * 4 + i;
                float v = acc2[rt][ct][i] + bv;
                sA[rowL * 128 + (((col >> 3) ^ (rowL & 15)) << 3) + (col & 7)] = f2bf_rn(v);
            }
        }
    }
    __syncthreads();
    {
        ushort8v* go = (ushort8v*)(H + (size_t)row0 * F);
#pragma unroll
        for (int i = 0; i < 8; ++i) {
            int fg = i * 256 + tid;
            int r = fg >> 4, u = fg & 15;
            if (row0 + r < NN)
                go[fg] = *(const ushort8v*)&sA[r * 128 + ((u ^ (r & 15)) << 3)];
        }
    }
}

// ---------------- launch ----------------
static inline size_t align256(size_t x) { return (x + 255) & ~(size_t)255; }

extern "C" void kernel_launch(void* const* d_in, const int* in_sizes, int n_in,
                              void* d_out, int out_size, void* d_ws, size_t ws_size,
                              hipStream_t stream) {
    const float* x   = (const float*)d_in[0];
    const int*   ei  = (const int*)d_in[1];
    const float* w11 = (const float*)d_in[2];
    const float* b11 = (const float*)d_in[3];
    const float* w12 = (const float*)d_in[4];
    const float* b12 = (const float*)d_in[5];
    const float* w21 = (const float*)d_in[6];
    const float* b21 = (const float*)d_in[7];
    const float* w22 = (const float*)d_in[8];
    const float* b22 = (const float*)d_in[9];
    const float* w31 = (const float*)d_in[10];
    const float* b31 = (const float*)d_in[11];
    const float* w32 = (const float*)d_in[12];
    const float* b32 = (const float*)d_in[13];
    float* out = (float*)d_out;

    const int* src = ei;
    const int* dst = ei + NE;

    char* ws = (char*)d_ws;
    size_t off = 0;
    unsigned short* Abuf = (unsigned short*)(ws + off); off += align256((size_t)NN * F * 2);
    unsigned short* Bbuf = (unsigned short*)(ws + off); off += align256((size_t)NN * F * 2);
    int* deg     = (int*)(ws + off); off += align256((size_t)NN * 4);
    int* row_ptr = (int*)(ws + off); off += align256((size_t)(NN + 1) * 4);
    int* cursor  = (int*)(ws + off); off += align256((size_t)NN * 4);
    int* partial = (int*)(ws + off); off += align256((size_t)NB_SCAN * 4);
    int* bcur    = (int*)(ws + off); off += align256((size_t)NBUCK * 4);
    int* csr     = (int*)(ws + off); off += align256((size_t)NE * 4);
    uint2* scratch = (uint2*)(ws + off); off += align256((size_t)NE * 8);
    unsigned short* whi[5];
    unsigned short* wlo[5];
    for (int i = 0; i < 5; ++i) {
        whi[i] = (unsigned short*)(ws + off); off += align256((size_t)128 * 128 * 2);
        wlo[i] = (unsigned short*)(ws + off); off += align256((size_t)128 * 128 * 2);
    }
    (void)ws_size;

    // ---- weight + input conversion ----
    WPack wp;
    wp.w[0] = w11; wp.w[1] = w12; wp.w[2] = w21; wp.w[3] = w22; wp.w[4] = w31;
    for (int i = 0; i < 5; ++i) { wp.hi[i] = whi[i]; wp.lo[i] = wlo[i]; }
    k_wsplit_all<<<320, 256, 0, stream>>>(wp);
    k_x2bf<<<(NN * F / 4 + 255) / 256, 256, 0, stream>>>(x, Abuf);

    // ---- CSR build ----
    (void)hipMemsetAsync(deg, 0, (size_t)NN * 4, stream);
    k_hist<<<2048, 256, 0, stream>>>(dst, deg);
    k_scan_part<<<NB_SCAN, 256, 0, stream>>>(deg, partial);
    k_scan_mid<<<1, 64, 0, stream>>>(partial);
    k_scan_final<<<NB_SCAN, 256, 0, stream>>>(deg, partial, row_ptr, cursor);
    k_bcur<<<(NBUCK + 255) / 256, 256, 0, stream>>>(row_ptr, bcur);
    k_scatterA<<<256, 256, 0, stream>>>(src, dst, bcur, scratch);
    k_fillB<<<NBUCK, 256, 0, stream>>>(row_ptr, scratch, cursor, csr);

    const int aggBlocks  = (NN + 7) / 8;
    const int mlpBlocks  = (NN + 127) / 128;

    // ---- layer 1 ----
    k_agg_bf<<<aggBlocks, 256, 0, stream>>>(Abuf, row_ptr, csr, Bbuf);
    k_mlp<0><<<mlpBlocks, 256, 0, stream>>>(Bbuf, whi[0], wlo[0], b11, whi[1], wlo[1], b12,
                                            nullptr, nullptr, Abuf, nullptr);
    // ---- layer 2 ----
    k_agg_bf<<<aggBlocks, 256, 0, stream>>>(Abuf, row_ptr, csr, Bbuf);
    k_mlp<0><<<mlpBlocks, 256, 0, stream>>>(Bbuf, whi[2], wlo[2], b21, whi[3], wlo[3], b22,
                                            nullptr, nullptr, Abuf, nullptr);
    // ---- layer 3 ----
    k_agg_bf<<<aggBlocks, 256, 0, stream>>>(Abuf, row_ptr, csr, Bbuf);
    k_mlp<1><<<mlpBlocks, 256, 0, stream>>>(Bbuf, whi[4], wlo[4], b31, nullptr, nullptr, nullptr,
                                            w32, b32, nullptr, out);
}